// Round 7
// baseline (15970.258 us; speedup 1.0000x reference)
//
#include <hip/hip_runtime.h>

#define LSEQ 2048
#define TAGS 12

typedef _Float16 half2v __attribute__((ext_vector_type(2)));

__device__ __forceinline__ float sigm(float x){ return 1.0f/(1.0f+__expf(-x)); }
__device__ __forceinline__ float tanh_fast(float x){ return 1.0f - 2.0f/(1.0f+__expf(2.0f*x)); }
__device__ __forceinline__ half2v pack2(float a, float b){
  half2v r; r.x=(_Float16)a; r.y=(_Float16)b; return r;
}

// K0: zero the exchange buffer (tag 0 never matches step tags in [1,2047]).
__global__ void init_kernel(unsigned long long* ex)
{
  int tid = blockIdx.x*256 + threadIdx.x;
  if (tid < 1024) ex[tid] = 0ull;
}

// K1: xg[d][t][row] = b_ih[row]+b_hh[row] + sum_e embed[sent[t]][e] * w_ih[row][e]
__global__ void xg_kernel(
    const int* sent, const float* embed,
    const float* w_ih_f, const float* b_ih_f, const float* b_hh_f,
    const float* w_ih_b, const float* b_ih_b, const float* b_hh_b,
    float* xg)
{
  __shared__ float x_sh[8][256];
  int tid = threadIdx.x;
  int t0 = blockIdx.x * 8;
  for (int i=0;i<8;++i){
    int idx = sent[t0+i];
    x_sh[i][tid] = embed[(size_t)idx*256 + tid];
  }
  __syncthreads();
  for (int ri=0; ri<8; ++ri){
    int r = ri*256 + tid;
    int d = r >> 10;
    int row = r & 1023;
    const float* wr = (d ? w_ih_b : w_ih_f) + (size_t)row*256;
    const float* bi = d ? b_ih_b : b_ih_f;
    const float* bh = d ? b_hh_b : b_hh_f;
    float acc[8];
    #pragma unroll
    for (int i=0;i<8;++i) acc[i]=0.f;
    for (int k0=0;k0<256;k0+=4){
      float4 p = *(const float4*)(wr + k0);
      #pragma unroll
      for (int i=0;i<8;++i){
        acc[i] += p.x*x_sh[i][k0] + p.y*x_sh[i][k0+1]
                + p.z*x_sh[i][k0+2] + p.w*x_sh[i][k0+3];
      }
    }
    float bias = bi[row] + bh[row];
    #pragma unroll
    for (int i=0;i<8;++i)
      xg[((size_t)d*LSEQ + (size_t)(t0+i))*1024 + row] = acc[i] + bias;
  }
}

// K2: bidirectional LSTM recurrence, 2 CUs per direction (256 thr, 1 wave/SIMD,
// 512-reg unified budget -> 256 f16-pair weight regs resident, NO spill).
// CU c owns units [128c,128c+128) for all 4 gates. Step structure hides the
// cross-CU latency: [send prev-h + history store] -> local-half dot ->
// volatile poll (no RMW) -> xg prefetch -> remote-half dot -> gates -> update.
__global__ __launch_bounds__(256,1) void lstm_rec(
    const float* __restrict__ w_hh_f, const float* __restrict__ w_hh_b,
    const float* __restrict__ xg, unsigned short* __restrict__ hstH,
    unsigned long long* __restrict__ ex)
{
  int blk = blockIdx.x;
  int d, c;
  if      (blk == 0){ d=0; c=0; }
  else if (blk == 8){ d=0; c=1; }
  else if (blk == 1){ d=1; c=0; }
  else if (blk == 9){ d=1; c=1; }
  else return;

  int tid = threadIdx.x;
  int g = tid >> 6, l = tid & 63;
  int r0 = g*256 + 128*c + l;       // gate rows (PyTorch order i,f,g,o)
  int r1 = r0 + 64;
  int lb = 64*c;                    // our pair indices [lb,lb+64)
  int rb = 64*(1-c);                // partner's pair indices
  const float* W = d ? w_hh_b : w_hh_f;
  const float* xgd = xg + (size_t)d*LSEQ*1024;
  unsigned short* hd = hstH + (size_t)d*LSEQ*256;
  unsigned long long* exd = ex + (size_t)d*256;   // [2 parity][128 pairs]

  __shared__ float gate_sh[512];
  __shared__ unsigned h2loc[64];    // our 64 packed f16 h-pairs

  half2v w0[128], w1[128];          // full-K f16 pair weights for rows r0,r1
  {
    const float* a = W + (size_t)r0*256;
    const float* b = W + (size_t)r1*256;
    #pragma unroll
    for (int k0=0;k0<64;++k0){
      float4 p = *(const float4*)(a + 4*k0);
      w0[2*k0]   = pack2(p.x,p.y);
      w0[2*k0+1] = pack2(p.z,p.w);
      float4 q = *(const float4*)(b + 4*k0);
      w1[2*k0]   = pack2(q.x,q.y);
      w1[2*k0+1] = pack2(q.z,q.w);
    }
  }
  if (tid < 64) h2loc[tid] = 0u;
  float c0 = 0.f, c1 = 0.f;
  unsigned hp = 0u;                 // our h-pair from previous step (tid<64)
  __syncthreads();

  int tf = d ? (LSEQ-1) : 0;
  float xg0 = xgd[(size_t)tf*1024 + r0];
  float xg1 = xgd[(size_t)tf*1024 + r1];

  for (int s=0;s<LSEQ;++s){
    // --- top: publish prev step's h to partner + h history (fire-and-forget)
    if (s > 0 && tid < 64){
      atomicExch(&exd[((s&1)<<7) + lb + tid],
                 ((unsigned long long)(unsigned)s << 32) | (unsigned long long)hp);
      int tp = d ? (LSEQ-s) : (s-1);
      *(unsigned*)&hd[(size_t)tp*256 + 128*c + 2*tid] = hp;
    }
    // --- local-half dot (h known since prev barrier)
    unsigned hl = h2loc[l];
    float a0=xg0, b0=0.f, a1=xg1, b1=0.f;
    #pragma unroll
    for (int k=0;k<64;k+=2){
      unsigned pa = __builtin_amdgcn_readlane(hl,k);
      unsigned pb = __builtin_amdgcn_readlane(hl,k+1);
      half2v va = __builtin_bit_cast(half2v,pa);
      half2v vb = __builtin_bit_cast(half2v,pb);
      a0 = __builtin_amdgcn_fdot2(va, w0[lb+k],   a0, false);
      a1 = __builtin_amdgcn_fdot2(va, w1[lb+k],   a1, false);
      b0 = __builtin_amdgcn_fdot2(vb, w0[lb+k+1], b0, false);
      b1 = __builtin_amdgcn_fdot2(vb, w1[lb+k+1], b1, false);
    }
    // --- poll partner's pair l (volatile read-only; no RMW contention)
    unsigned hr = 0u;
    if (s > 0){
      unsigned long long v;
      do { v = *(volatile const unsigned long long*)&exd[((s&1)<<7) + rb + l]; }
      while ((unsigned)(v>>32) != (unsigned)s);
      hr = (unsigned)v;
    }
    // --- prefetch next xg AFTER the poll (poll's vmcnt(0) must not wait on HBM)
    float nxg0 = 0.f, nxg1 = 0.f;
    if (s+1 < LSEQ){
      int tn = d ? (LSEQ-2-s) : (s+1);
      nxg0 = xgd[(size_t)tn*1024 + r0];
      nxg1 = xgd[(size_t)tn*1024 + r1];
    }
    // --- remote-half dot
    #pragma unroll
    for (int k=0;k<64;k+=2){
      unsigned pa = __builtin_amdgcn_readlane(hr,k);
      unsigned pb = __builtin_amdgcn_readlane(hr,k+1);
      half2v va = __builtin_bit_cast(half2v,pa);
      half2v vb = __builtin_bit_cast(half2v,pb);
      a0 = __builtin_amdgcn_fdot2(va, w0[rb+k],   a0, false);
      a1 = __builtin_amdgcn_fdot2(va, w1[rb+k],   a1, false);
      b0 = __builtin_amdgcn_fdot2(vb, w0[rb+k+1], b0, false);
      b1 = __builtin_amdgcn_fdot2(vb, w1[rb+k+1], b1, false);
    }
    float pre0 = a0 + b0;
    float pre1 = a1 + b1;
    float act0, act1;
    if (g == 2){ act0 = tanh_fast(pre0); act1 = tanh_fast(pre1); }
    else       { act0 = sigm(pre0);      act1 = sigm(pre1); }
    gate_sh[g*128 + l]      = act0;
    gate_sh[g*128 + 64 + l] = act1;
    xg0 = nxg0; xg1 = nxg1;
    __syncthreads();
    if (tid < 64){
      int m = tid;
      float2 gi = *(const float2*)&gate_sh[      2*m];
      float2 gf = *(const float2*)&gate_sh[128 + 2*m];
      float2 gg = *(const float2*)&gate_sh[256 + 2*m];
      float2 go = *(const float2*)&gate_sh[384 + 2*m];
      c0 = gf.x*c0 + gi.x*gg.x;
      c1 = gf.y*c1 + gi.y*gg.y;
      float h0 = go.x * tanh_fast(c0);
      float h1 = go.y * tanh_fast(c1);
      hp = __builtin_bit_cast(unsigned, pack2(h0,h1));
      h2loc[m] = hp;
    }
    __syncthreads();
  }
  // final h history store (step LSEQ-1)
  if (tid < 64){
    int tl = d ? 0 : (LSEQ-1);
    *(unsigned*)&hd[(size_t)tl*256 + 128*c + 2*tid] = hp;
  }
}

// K3: feats[t][tag] = b_out[tag] + [hf|hb] . w_out[tag]   (h history is f16)
__global__ void feats_kernel(
    const unsigned short* hstH, const float* w_out, const float* b_out,
    float* feats)
{
  __shared__ float w_sh[12*520];
  __shared__ float h_sh[16*520];
  const _Float16* hf = (const _Float16*)hstH;
  int tid=threadIdx.x;
  int t0=blockIdx.x*16;
  for (int i=tid;i<12*512;i+=256){ int tag=i>>9,k=i&511; w_sh[tag*520+k]=w_out[i]; }
  for (int i=tid;i<16*512;i+=256){
    int tt=i>>9,k=i&511;
    float v = (k<256)? (float)hf[(size_t)(t0+tt)*256+k]
                     : (float)hf[(size_t)(LSEQ+t0+tt)*256 + (k-256)];
    h_sh[tt*520+k]=v;
  }
  __syncthreads();
  if (tid<192){
    int tt=tid/12, tag=tid%12;
    const float* wr=&w_sh[tag*520];
    const float* hr=&h_sh[tt*520];
    float acc=b_out[tag];
    for (int k=0;k<512;k+=4){
      float4 a=*(const float4*)(wr+k);
      float4 b=*(const float4*)(hr+k);
      acc += a.x*b.x+a.y*b.y+a.z*b.z+a.w*b.w;
    }
    feats[(size_t)(t0+tt)*12+tag]=acc;
  }
}

// K4: Viterbi DP: feats in LDS, v register-resident via readlane; parallel
// block-composed backtrack.
__global__ void BiLSTM_CRF_14405320311361_kernel(
    const float* feats, const float* trans, float* outp)
{
  __shared__ float fsh[LSEQ*12];           // 96 KB
  __shared__ unsigned char bps[LSEQ*12];   // 24 KB
  __shared__ float term_sh[16];
  __shared__ int ibuf[66];
  __shared__ unsigned char fmap[64*12];
  int tid = threadIdx.x;
  for (int i=tid; i<LSEQ*12/4; i+=256)
    *(float4*)&fsh[4*i] = *(const float4*)&feats[4*i];
  __syncthreads();

  int lane = tid & 63;
  int fl = (lane<12) ? lane : 0;
  float vn = 0.f;
  if (tid < 64){
    float tr[12];
    #pragma unroll
    for (int p=0;p<12;++p) tr[p] = trans[fl*12+p];
    vn = (lane==10) ? 0.f : -10000.f;     // START=10
    float fa = fsh[fl];
    float fb = fsh[12+fl];
    for (int t=0;t<LSEQ;++t){
      unsigned vu = __float_as_uint(vn);
      float best; int bp; float sc;
      best = tr[0] + __uint_as_float(__builtin_amdgcn_readlane(vu,0)); bp = 0;
      sc = tr[1]  + __uint_as_float(__builtin_amdgcn_readlane(vu,1));  if(sc>best){best=sc;bp=1;}
      sc = tr[2]  + __uint_as_float(__builtin_amdgcn_readlane(vu,2));  if(sc>best){best=sc;bp=2;}
      sc = tr[3]  + __uint_as_float(__builtin_amdgcn_readlane(vu,3));  if(sc>best){best=sc;bp=3;}
      sc = tr[4]  + __uint_as_float(__builtin_amdgcn_readlane(vu,4));  if(sc>best){best=sc;bp=4;}
      sc = tr[5]  + __uint_as_float(__builtin_amdgcn_readlane(vu,5));  if(sc>best){best=sc;bp=5;}
      sc = tr[6]  + __uint_as_float(__builtin_amdgcn_readlane(vu,6));  if(sc>best){best=sc;bp=6;}
      sc = tr[7]  + __uint_as_float(__builtin_amdgcn_readlane(vu,7));  if(sc>best){best=sc;bp=7;}
      sc = tr[8]  + __uint_as_float(__builtin_amdgcn_readlane(vu,8));  if(sc>best){best=sc;bp=8;}
      sc = tr[9]  + __uint_as_float(__builtin_amdgcn_readlane(vu,9));  if(sc>best){best=sc;bp=9;}
      sc = tr[10] + __uint_as_float(__builtin_amdgcn_readlane(vu,10)); if(sc>best){best=sc;bp=10;}
      sc = tr[11] + __uint_as_float(__builtin_amdgcn_readlane(vu,11)); if(sc>best){best=sc;bp=11;}
      vn = best + fa;
      fa = fb;
      if (t+2 < LSEQ) fb = fsh[(t+2)*12+fl];
      if (lane<12) bps[t*12+lane] = (unsigned char)bp;
    }
  }
  if (tid < 12) term_sh[tid] = vn + trans[11*12+tid];   // STOP=11
  __syncthreads();
  if (tid == 0){
    float bs=term_sh[0]; int bt=0;
    for (int p=1;p<12;++p){ if (term_sh[p]>bs){bs=term_sh[p];bt=p;} }
    outp[0] = bs;
    ibuf[64] = bt;
  }
  __syncthreads();
  if (tid < 64){
    int b = tid;
    int f[12];
    int thi = b*32+31;
    #pragma unroll
    for (int x=0;x<12;++x) f[x] = bps[thi*12+x];
    for (int t=thi-1; t>=b*32; --t){
      int base = t*12;
      #pragma unroll
      for (int x=0;x<12;++x) f[x] = bps[base + f[x]];
    }
    #pragma unroll
    for (int x=0;x<12;++x) fmap[b*12+x] = (unsigned char)f[x];
  }
  __syncthreads();
  if (tid == 0){
    int tag = ibuf[64];
    for (int b=63;b>=0;--b){ ibuf[b]=tag; tag = fmap[b*12+tag]; }
  }
  __syncthreads();
  if (tid < 64){
    int b = tid;
    int tag = ibuf[b];
    for (int t=b*32+31; t>=b*32; --t){
      outp[1+t] = (float)tag;
      tag = bps[t*12+tag];
    }
  }
}

extern "C" void kernel_launch(void* const* d_in, const int* in_sizes, int n_in,
                              void* d_out, int out_size, void* d_ws, size_t ws_size,
                              hipStream_t stream) {
  const int*   sent   = (const int*)d_in[0];
  const float* embed  = (const float*)d_in[1];
  const float* w_ih_f = (const float*)d_in[2];
  const float* w_hh_f = (const float*)d_in[3];
  const float* b_ih_f = (const float*)d_in[4];
  const float* b_hh_f = (const float*)d_in[5];
  const float* w_ih_b = (const float*)d_in[6];
  const float* w_hh_b = (const float*)d_in[7];
  const float* b_ih_b = (const float*)d_in[8];
  const float* b_hh_b = (const float*)d_in[9];
  const float* w_out  = (const float*)d_in[10];
  const float* b_out  = (const float*)d_in[11];
  const float* trans  = (const float*)d_in[12];

  float* xg = (float*)d_ws;                                           // [2][L][1024] f32 = 16 MB
  unsigned short* hstH = (unsigned short*)(xg + (size_t)2*LSEQ*1024); // [2][L][256] f16 = 2 MB
  unsigned long long* ex = (unsigned long long*)(hstH + (size_t)2*LSEQ*256); // 8 KB
  float* feats = (float*)(ex + 1024);                                 // [L][12] f32 = 96 KB
  float* outp  = (float*)d_out;

  init_kernel<<<dim3(4), dim3(256), 0, stream>>>(ex);
  xg_kernel<<<dim3(LSEQ/8), dim3(256), 0, stream>>>(
      sent, embed, w_ih_f, b_ih_f, b_hh_f, w_ih_b, b_ih_b, b_hh_b, xg);
  lstm_rec<<<dim3(16), dim3(256), 0, stream>>>(w_hh_f, w_hh_b, xg, hstH, ex);
  feats_kernel<<<dim3(LSEQ/16), dim3(256), 0, stream>>>(hstH, w_out, b_out, feats);
  BiLSTM_CRF_14405320311361_kernel<<<dim3(1), dim3(256), 0, stream>>>(feats, trans, outp);
}

// Round 8
// 5658.694 us; speedup vs baseline: 2.8223x; 2.8223x over previous
//
#include <hip/hip_runtime.h>

#define LSEQ 2048
#define TAGS 12

typedef _Float16 half2v __attribute__((ext_vector_type(2)));

__device__ __forceinline__ float sigm(float x){ return 1.0f/(1.0f+__expf(-x)); }
__device__ __forceinline__ float tanh_fast(float x){ return 1.0f - 2.0f/(1.0f+__expf(2.0f*x)); }
__device__ __forceinline__ half2v pack2(float a, float b){
  half2v r; r.x=(_Float16)a; r.y=(_Float16)b; return r;
}

// K0: zero the exchange buffer (tag 0 never matches step tags in [1,2047]).
__global__ void init_kernel(unsigned long long* ex)
{
  int tid = blockIdx.x*256 + threadIdx.x;
  if (tid < 1024) ex[tid] = 0ull;
}

// K1: xg[d][t][row] = b_ih[row]+b_hh[row] + sum_e embed[sent[t]][e] * w_ih[row][e]
__global__ void xg_kernel(
    const int* sent, const float* embed,
    const float* w_ih_f, const float* b_ih_f, const float* b_hh_f,
    const float* w_ih_b, const float* b_ih_b, const float* b_hh_b,
    float* xg)
{
  __shared__ float x_sh[8][256];
  int tid = threadIdx.x;
  int t0 = blockIdx.x * 8;
  for (int i=0;i<8;++i){
    int idx = sent[t0+i];
    x_sh[i][tid] = embed[(size_t)idx*256 + tid];
  }
  __syncthreads();
  for (int ri=0; ri<8; ++ri){
    int r = ri*256 + tid;
    int d = r >> 10;
    int row = r & 1023;
    const float* wr = (d ? w_ih_b : w_ih_f) + (size_t)row*256;
    const float* bi = d ? b_ih_b : b_ih_f;
    const float* bh = d ? b_hh_b : b_hh_f;
    float acc[8];
    #pragma unroll
    for (int i=0;i<8;++i) acc[i]=0.f;
    for (int k0=0;k0<256;k0+=4){
      float4 p = *(const float4*)(wr + k0);
      #pragma unroll
      for (int i=0;i<8;++i){
        acc[i] += p.x*x_sh[i][k0] + p.y*x_sh[i][k0+1]
                + p.z*x_sh[i][k0+2] + p.w*x_sh[i][k0+3];
      }
    }
    float bias = bi[row] + bh[row];
    #pragma unroll
    for (int i=0;i<8;++i)
      xg[((size_t)d*LSEQ + (size_t)(t0+i))*1024 + row] = acc[i] + bias;
  }
}

// K2: bidirectional LSTM recurrence, 2 CUs per direction (256 thr, 1 wave/SIMD).
// Weight registers hold a PERMUTED column layout: w[0..63] = this CU's local
// 64 column-pairs, w[64..127] = partner's pairs -> all register indices are
// compile-time constants (dynamic indexing would demote to scratch: round-7
// lesson, VGPR 80 + 12 GB scratch traffic). Step: [send prev-h + history]
// -> local-half dot -> volatile poll -> xg prefetch -> remote-half dot ->
// gates -> update.
__global__ __launch_bounds__(256,1) void lstm_rec(
    const float* __restrict__ w_hh_f, const float* __restrict__ w_hh_b,
    const float* __restrict__ xg, unsigned short* __restrict__ hstH,
    unsigned long long* __restrict__ ex)
{
  int blk = blockIdx.x;
  int d, c;
  if      (blk == 0){ d=0; c=0; }
  else if (blk == 8){ d=0; c=1; }
  else if (blk == 1){ d=1; c=0; }
  else if (blk == 9){ d=1; c=1; }
  else return;

  int tid = threadIdx.x;
  int g = tid >> 6, l = tid & 63;
  int r0 = g*256 + 128*c + l;       // gate rows (PyTorch order i,f,g,o)
  int r1 = r0 + 64;
  int lb = 64*c;                    // our pair indices [lb,lb+64)
  int rb = 64*(1-c);                // partner's pair indices
  const float* W = d ? w_hh_b : w_hh_f;
  const float* xgd = xg + (size_t)d*LSEQ*1024;
  unsigned short* hd = hstH + (size_t)d*LSEQ*256;
  unsigned long long* exd = ex + (size_t)d*256;   // [2 parity][128 pairs]

  __shared__ float gate_sh[512];
  __shared__ unsigned h2loc[64];    // our 64 packed f16 h-pairs

  // Permuted-column weight load: [0..63]=local pairs, [64..127]=remote pairs.
  half2v w0[128], w1[128];
  {
    const float* aL = W + (size_t)r0*256 + 128*c;
    const float* aR = W + (size_t)r0*256 + 128*(1-c);
    const float* bL = W + (size_t)r1*256 + 128*c;
    const float* bR = W + (size_t)r1*256 + 128*(1-c);
    #pragma unroll
    for (int k0=0;k0<32;++k0){
      float4 p = *(const float4*)(aL + 4*k0);
      w0[2*k0]      = pack2(p.x,p.y);
      w0[2*k0+1]    = pack2(p.z,p.w);
      float4 q = *(const float4*)(aR + 4*k0);
      w0[64+2*k0]   = pack2(q.x,q.y);
      w0[64+2*k0+1] = pack2(q.z,q.w);
      float4 r = *(const float4*)(bL + 4*k0);
      w1[2*k0]      = pack2(r.x,r.y);
      w1[2*k0+1]    = pack2(r.z,r.w);
      float4 t = *(const float4*)(bR + 4*k0);
      w1[64+2*k0]   = pack2(t.x,t.y);
      w1[64+2*k0+1] = pack2(t.z,t.w);
    }
  }
  if (tid < 64) h2loc[tid] = 0u;
  float c0 = 0.f, c1 = 0.f;
  unsigned hp = 0u;                 // our h-pair from previous step (tid<64)
  __syncthreads();

  int tf = d ? (LSEQ-1) : 0;
  float xg0 = xgd[(size_t)tf*1024 + r0];
  float xg1 = xgd[(size_t)tf*1024 + r1];

  for (int s=0;s<LSEQ;++s){
    // --- top: publish prev step's h to partner + h history (fire-and-forget)
    if (s > 0 && tid < 64){
      atomicExch(&exd[((s&1)<<7) + lb + tid],
                 ((unsigned long long)(unsigned)s << 32) | (unsigned long long)hp);
      int tp = d ? (LSEQ-s) : (s-1);
      *(unsigned*)&hd[(size_t)tp*256 + 128*c + 2*tid] = hp;
    }
    // --- local-half dot (h2loc[l] = global pair lb+l; w[k] = column pair lb+k)
    unsigned hl = h2loc[l];
    float a0=xg0, b0=0.f, a1=xg1, b1=0.f;
    #pragma unroll
    for (int k=0;k<64;k+=2){
      unsigned pa = __builtin_amdgcn_readlane(hl,k);
      unsigned pb = __builtin_amdgcn_readlane(hl,k+1);
      half2v va = __builtin_bit_cast(half2v,pa);
      half2v vb = __builtin_bit_cast(half2v,pb);
      a0 = __builtin_amdgcn_fdot2(va, w0[k],   a0, false);
      a1 = __builtin_amdgcn_fdot2(va, w1[k],   a1, false);
      b0 = __builtin_amdgcn_fdot2(vb, w0[k+1], b0, false);
      b1 = __builtin_amdgcn_fdot2(vb, w1[k+1], b1, false);
    }
    // --- poll partner's pair rb+l (volatile read-only; no RMW contention)
    unsigned hr = 0u;
    if (s > 0){
      unsigned long long v;
      do { v = *(volatile const unsigned long long*)&exd[((s&1)<<7) + rb + l]; }
      while ((unsigned)(v>>32) != (unsigned)s);
      hr = (unsigned)v;
    }
    // --- prefetch next xg AFTER the poll (poll's waits must not drain HBM loads)
    float nxg0 = 0.f, nxg1 = 0.f;
    if (s+1 < LSEQ){
      int tn = d ? (LSEQ-2-s) : (s+1);
      nxg0 = xgd[(size_t)tn*1024 + r0];
      nxg1 = xgd[(size_t)tn*1024 + r1];
    }
    // --- remote-half dot (hr lane k = global pair rb+k; w[64+k] = pair rb+k)
    #pragma unroll
    for (int k=0;k<64;k+=2){
      unsigned pa = __builtin_amdgcn_readlane(hr,k);
      unsigned pb = __builtin_amdgcn_readlane(hr,k+1);
      half2v va = __builtin_bit_cast(half2v,pa);
      half2v vb = __builtin_bit_cast(half2v,pb);
      a0 = __builtin_amdgcn_fdot2(va, w0[64+k],   a0, false);
      a1 = __builtin_amdgcn_fdot2(va, w1[64+k],   a1, false);
      b0 = __builtin_amdgcn_fdot2(vb, w0[64+k+1], b0, false);
      b1 = __builtin_amdgcn_fdot2(vb, w1[64+k+1], b1, false);
    }
    float pre0 = a0 + b0;
    float pre1 = a1 + b1;
    float act0, act1;
    if (g == 2){ act0 = tanh_fast(pre0); act1 = tanh_fast(pre1); }
    else       { act0 = sigm(pre0);      act1 = sigm(pre1); }
    gate_sh[g*128 + l]      = act0;
    gate_sh[g*128 + 64 + l] = act1;
    xg0 = nxg0; xg1 = nxg1;
    __syncthreads();
    if (tid < 64){
      int m = tid;
      float2 gi = *(const float2*)&gate_sh[      2*m];
      float2 gf = *(const float2*)&gate_sh[128 + 2*m];
      float2 gg = *(const float2*)&gate_sh[256 + 2*m];
      float2 go = *(const float2*)&gate_sh[384 + 2*m];
      c0 = gf.x*c0 + gi.x*gg.x;
      c1 = gf.y*c1 + gi.y*gg.y;
      float h0 = go.x * tanh_fast(c0);
      float h1 = go.y * tanh_fast(c1);
      hp = __builtin_bit_cast(unsigned, pack2(h0,h1));
      h2loc[m] = hp;
    }
    __syncthreads();
  }
  // final h history store (step LSEQ-1)
  if (tid < 64){
    int tl = d ? 0 : (LSEQ-1);
    *(unsigned*)&hd[(size_t)tl*256 + 128*c + 2*tid] = hp;
  }
}

// K3: feats[t][tag] = b_out[tag] + [hf|hb] . w_out[tag]   (h history is f16)
__global__ void feats_kernel(
    const unsigned short* hstH, const float* w_out, const float* b_out,
    float* feats)
{
  __shared__ float w_sh[12*520];
  __shared__ float h_sh[16*520];
  const _Float16* hf = (const _Float16*)hstH;
  int tid=threadIdx.x;
  int t0=blockIdx.x*16;
  for (int i=tid;i<12*512;i+=256){ int tag=i>>9,k=i&511; w_sh[tag*520+k]=w_out[i]; }
  for (int i=tid;i<16*512;i+=256){
    int tt=i>>9,k=i&511;
    float v = (k<256)? (float)hf[(size_t)(t0+tt)*256+k]
                     : (float)hf[(size_t)(LSEQ+t0+tt)*256 + (k-256)];
    h_sh[tt*520+k]=v;
  }
  __syncthreads();
  if (tid<192){
    int tt=tid/12, tag=tid%12;
    const float* wr=&w_sh[tag*520];
    const float* hr=&h_sh[tt*520];
    float acc=b_out[tag];
    for (int k=0;k<512;k+=4){
      float4 a=*(const float4*)(wr+k);
      float4 b=*(const float4*)(hr+k);
      acc += a.x*b.x+a.y*b.y+a.z*b.z+a.w*b.w;
    }
    feats[(size_t)(t0+tt)*12+tag]=acc;
  }
}

// K4: Viterbi DP: feats in LDS, v register-resident via readlane; parallel
// block-composed backtrack.
__global__ void BiLSTM_CRF_14405320311361_kernel(
    const float* feats, const float* trans, float* outp)
{
  __shared__ float fsh[LSEQ*12];           // 96 KB
  __shared__ unsigned char bps[LSEQ*12];   // 24 KB
  __shared__ float term_sh[16];
  __shared__ int ibuf[66];
  __shared__ unsigned char fmap[64*12];
  int tid = threadIdx.x;
  for (int i=tid; i<LSEQ*12/4; i+=256)
    *(float4*)&fsh[4*i] = *(const float4*)&feats[4*i];
  __syncthreads();

  int lane = tid & 63;
  int fl = (lane<12) ? lane : 0;
  float vn = 0.f;
  if (tid < 64){
    float tr[12];
    #pragma unroll
    for (int p=0;p<12;++p) tr[p] = trans[fl*12+p];
    vn = (lane==10) ? 0.f : -10000.f;     // START=10
    float fa = fsh[fl];
    float fb = fsh[12+fl];
    for (int t=0;t<LSEQ;++t){
      unsigned vu = __float_as_uint(vn);
      float best; int bp; float sc;
      best = tr[0] + __uint_as_float(__builtin_amdgcn_readlane(vu,0)); bp = 0;
      sc = tr[1]  + __uint_as_float(__builtin_amdgcn_readlane(vu,1));  if(sc>best){best=sc;bp=1;}
      sc = tr[2]  + __uint_as_float(__builtin_amdgcn_readlane(vu,2));  if(sc>best){best=sc;bp=2;}
      sc = tr[3]  + __uint_as_float(__builtin_amdgcn_readlane(vu,3));  if(sc>best){best=sc;bp=3;}
      sc = tr[4]  + __uint_as_float(__builtin_amdgcn_readlane(vu,4));  if(sc>best){best=sc;bp=4;}
      sc = tr[5]  + __uint_as_float(__builtin_amdgcn_readlane(vu,5));  if(sc>best){best=sc;bp=5;}
      sc = tr[6]  + __uint_as_float(__builtin_amdgcn_readlane(vu,6));  if(sc>best){best=sc;bp=6;}
      sc = tr[7]  + __uint_as_float(__builtin_amdgcn_readlane(vu,7));  if(sc>best){best=sc;bp=7;}
      sc = tr[8]  + __uint_as_float(__builtin_amdgcn_readlane(vu,8));  if(sc>best){best=sc;bp=8;}
      sc = tr[9]  + __uint_as_float(__builtin_amdgcn_readlane(vu,9));  if(sc>best){best=sc;bp=9;}
      sc = tr[10] + __uint_as_float(__builtin_amdgcn_readlane(vu,10)); if(sc>best){best=sc;bp=10;}
      sc = tr[11] + __uint_as_float(__builtin_amdgcn_readlane(vu,11)); if(sc>best){best=sc;bp=11;}
      vn = best + fa;
      fa = fb;
      if (t+2 < LSEQ) fb = fsh[(t+2)*12+fl];
      if (lane<12) bps[t*12+lane] = (unsigned char)bp;
    }
  }
  if (tid < 12) term_sh[tid] = vn + trans[11*12+tid];   // STOP=11
  __syncthreads();
  if (tid == 0){
    float bs=term_sh[0]; int bt=0;
    for (int p=1;p<12;++p){ if (term_sh[p]>bs){bs=term_sh[p];bt=p;} }
    outp[0] = bs;
    ibuf[64] = bt;
  }
  __syncthreads();
  if (tid < 64){
    int b = tid;
    int f[12];
    int thi = b*32+31;
    #pragma unroll
    for (int x=0;x<12;++x) f[x] = bps[thi*12+x];
    for (int t=thi-1; t>=b*32; --t){
      int base = t*12;
      #pragma unroll
      for (int x=0;x<12;++x) f[x] = bps[base + f[x]];
    }
    #pragma unroll
    for (int x=0;x<12;++x) fmap[b*12+x] = (unsigned char)f[x];
  }
  __syncthreads();
  if (tid == 0){
    int tag = ibuf[64];
    for (int b=63;b>=0;--b){ ibuf[b]=tag; tag = fmap[b*12+tag]; }
  }
  __syncthreads();
  if (tid < 64){
    int b = tid;
    int tag = ibuf[b];
    for (int t=b*32+31; t>=b*32; --t){
      outp[1+t] = (float)tag;
      tag = bps[t*12+tag];
    }
  }
}

extern "C" void kernel_launch(void* const* d_in, const int* in_sizes, int n_in,
                              void* d_out, int out_size, void* d_ws, size_t ws_size,
                              hipStream_t stream) {
  const int*   sent   = (const int*)d_in[0];
  const float* embed  = (const float*)d_in[1];
  const float* w_ih_f = (const float*)d_in[2];
  const float* w_hh_f = (const float*)d_in[3];
  const float* b_ih_f = (const float*)d_in[4];
  const float* b_hh_f = (const float*)d_in[5];
  const float* w_ih_b = (const float*)d_in[6];
  const float* w_hh_b = (const float*)d_in[7];
  const float* b_ih_b = (const float*)d_in[8];
  const float* b_hh_b = (const float*)d_in[9];
  const float* w_out  = (const float*)d_in[10];
  const float* b_out  = (const float*)d_in[11];
  const float* trans  = (const float*)d_in[12];

  float* xg = (float*)d_ws;                                           // [2][L][1024] f32 = 16 MB
  unsigned short* hstH = (unsigned short*)(xg + (size_t)2*LSEQ*1024); // [2][L][256] f16 = 2 MB
  unsigned long long* ex = (unsigned long long*)(hstH + (size_t)2*LSEQ*256); // 8 KB
  float* feats = (float*)(ex + 1024);                                 // [L][12] f32 = 96 KB
  float* outp  = (float*)d_out;

  init_kernel<<<dim3(4), dim3(256), 0, stream>>>(ex);
  xg_kernel<<<dim3(LSEQ/8), dim3(256), 0, stream>>>(
      sent, embed, w_ih_f, b_ih_f, b_hh_f, w_ih_b, b_ih_b, b_hh_b, xg);
  lstm_rec<<<dim3(16), dim3(256), 0, stream>>>(w_hh_f, w_hh_b, xg, hstH, ex);
  feats_kernel<<<dim3(LSEQ/16), dim3(256), 0, stream>>>(hstH, w_out, b_out, feats);
  BiLSTM_CRF_14405320311361_kernel<<<dim3(1), dim3(256), 0, stream>>>(feats, trans, outp);
}

// Round 9
// 5054.957 us; speedup vs baseline: 3.1593x; 1.1194x over previous
//
#include <hip/hip_runtime.h>

#define LSEQ 2048
#define TAGS 12

typedef _Float16 half2v __attribute__((ext_vector_type(2)));

__device__ __forceinline__ float sigm(float x){ return 1.0f/(1.0f+__expf(-x)); }
__device__ __forceinline__ float tanh_fast(float x){ return 1.0f - 2.0f/(1.0f+__expf(2.0f*x)); }
__device__ __forceinline__ half2v pack2(float a, float b){
  half2v r; r.x=(_Float16)a; r.y=(_Float16)b; return r;
}

// K0: zero the exchange buffer (tag 0 never matches step tags in [1,2047]).
__global__ void init_kernel(unsigned long long* ex)
{
  int tid = blockIdx.x*256 + threadIdx.x;
  if (tid < 1024) ex[tid] = 0ull;
}

// K1: xg[d][t][row] = b_ih[row]+b_hh[row] + sum_e embed[sent[t]][e] * w_ih[row][e]
__global__ void xg_kernel(
    const int* sent, const float* embed,
    const float* w_ih_f, const float* b_ih_f, const float* b_hh_f,
    const float* w_ih_b, const float* b_ih_b, const float* b_hh_b,
    float* xg)
{
  __shared__ float x_sh[8][256];
  int tid = threadIdx.x;
  int t0 = blockIdx.x * 8;
  for (int i=0;i<8;++i){
    int idx = sent[t0+i];
    x_sh[i][tid] = embed[(size_t)idx*256 + tid];
  }
  __syncthreads();
  for (int ri=0; ri<8; ++ri){
    int r = ri*256 + tid;
    int d = r >> 10;
    int row = r & 1023;
    const float* wr = (d ? w_ih_b : w_ih_f) + (size_t)row*256;
    const float* bi = d ? b_ih_b : b_ih_f;
    const float* bh = d ? b_hh_b : b_hh_f;
    float acc[8];
    #pragma unroll
    for (int i=0;i<8;++i) acc[i]=0.f;
    for (int k0=0;k0<256;k0+=4){
      float4 p = *(const float4*)(wr + k0);
      #pragma unroll
      for (int i=0;i<8;++i){
        acc[i] += p.x*x_sh[i][k0] + p.y*x_sh[i][k0+1]
                + p.z*x_sh[i][k0+2] + p.w*x_sh[i][k0+3];
      }
    }
    float bias = bi[row] + bh[row];
    #pragma unroll
    for (int i=0;i<8;++i)
      xg[((size_t)d*LSEQ + (size_t)(t0+i))*1024 + row] = acc[i] + bias;
  }
}

// K2: bidirectional LSTM recurrence, 2 CUs per direction (256 thr, 1 wave/SIMD,
// permuted-column weights register-resident: w[0..63]=local pairs, w[64..127]=
// remote pairs, all indices compile-time). Exchange via (tag<<32|h2) words:
// sender atomicExch (device scope); receiver polls with RELAXED AGENT-scope
// atomic loads (sc1: bypasses stale local L2 -- round-8's volatile poll spun
// ~700 iters/step re-fetching stale lines, 11.4 GB FETCH). First poll load is
// issued BEFORE the local-half dot so its latency hides under ~770 cyc of VALU.
__global__ __launch_bounds__(256,1) void lstm_rec(
    const float* __restrict__ w_hh_f, const float* __restrict__ w_hh_b,
    const float* __restrict__ xg, unsigned short* __restrict__ hstH,
    unsigned long long* __restrict__ ex)
{
  int blk = blockIdx.x;
  int d, c;
  if      (blk == 0){ d=0; c=0; }
  else if (blk == 8){ d=0; c=1; }
  else if (blk == 1){ d=1; c=0; }
  else if (blk == 9){ d=1; c=1; }
  else return;

  int tid = threadIdx.x;
  int g = tid >> 6, l = tid & 63;
  int r0 = g*256 + 128*c + l;       // gate rows (PyTorch order i,f,g,o)
  int r1 = r0 + 64;
  int lb = 64*c;                    // our pair indices [lb,lb+64)
  int rb = 64*(1-c);                // partner's pair indices
  const float* W = d ? w_hh_b : w_hh_f;
  const float* xgd = xg + (size_t)d*LSEQ*1024;
  unsigned short* hd = hstH + (size_t)d*LSEQ*256;
  unsigned long long* exd = ex + (size_t)d*256;   // [2 parity][128 pairs]

  __shared__ float gate_sh[512];
  __shared__ unsigned h2loc[64];    // our 64 packed f16 h-pairs

  // Permuted-column weight load: [0..63]=local pairs, [64..127]=remote pairs.
  half2v w0[128], w1[128];
  {
    const float* aL = W + (size_t)r0*256 + 128*c;
    const float* aR = W + (size_t)r0*256 + 128*(1-c);
    const float* bL = W + (size_t)r1*256 + 128*c;
    const float* bR = W + (size_t)r1*256 + 128*(1-c);
    #pragma unroll
    for (int k0=0;k0<32;++k0){
      float4 p = *(const float4*)(aL + 4*k0);
      w0[2*k0]      = pack2(p.x,p.y);
      w0[2*k0+1]    = pack2(p.z,p.w);
      float4 q = *(const float4*)(aR + 4*k0);
      w0[64+2*k0]   = pack2(q.x,q.y);
      w0[64+2*k0+1] = pack2(q.z,q.w);
      float4 r = *(const float4*)(bL + 4*k0);
      w1[2*k0]      = pack2(r.x,r.y);
      w1[2*k0+1]    = pack2(r.z,r.w);
      float4 t = *(const float4*)(bR + 4*k0);
      w1[64+2*k0]   = pack2(t.x,t.y);
      w1[64+2*k0+1] = pack2(t.z,t.w);
    }
  }
  if (tid < 64) h2loc[tid] = 0u;
  float c0 = 0.f, c1 = 0.f;
  unsigned hp = 0u;                 // our h-pair from previous step (tid<64)
  __syncthreads();

  int tf = d ? (LSEQ-1) : 0;
  float xg0 = xgd[(size_t)tf*1024 + r0];
  float xg1 = xgd[(size_t)tf*1024 + r1];

  for (int s=0;s<LSEQ;++s){
    // --- top: publish prev step's h to partner + h history (fire-and-forget)
    if (s > 0 && tid < 64){
      atomicExch(&exd[((s&1)<<7) + lb + tid],
                 ((unsigned long long)(unsigned)s << 32) | (unsigned long long)hp);
      int tp = d ? (LSEQ-s) : (s-1);
      *(unsigned*)&hd[(size_t)tp*256 + 128*c + 2*tid] = hp;
    }
    // --- early poll issue: latency hides under the local-half dot below
    unsigned long long v0 = 0ull;
    if (s > 0)
      v0 = __hip_atomic_load(&exd[((s&1)<<7) + rb + l],
                             __ATOMIC_RELAXED, __HIP_MEMORY_SCOPE_AGENT);
    // --- local-half dot (h2loc[l] = global pair lb+l; w[k] = column pair lb+k)
    unsigned hl = h2loc[l];
    float a0=xg0, b0=0.f, a1=xg1, b1=0.f;
    #pragma unroll
    for (int k=0;k<64;k+=2){
      unsigned pa = __builtin_amdgcn_readlane(hl,k);
      unsigned pb = __builtin_amdgcn_readlane(hl,k+1);
      half2v va = __builtin_bit_cast(half2v,pa);
      half2v vb = __builtin_bit_cast(half2v,pb);
      a0 = __builtin_amdgcn_fdot2(va, w0[k],   a0, false);
      a1 = __builtin_amdgcn_fdot2(va, w1[k],   a1, false);
      b0 = __builtin_amdgcn_fdot2(vb, w0[k+1], b0, false);
      b1 = __builtin_amdgcn_fdot2(vb, w1[k+1], b1, false);
    }
    // --- poll partner's pair rb+l (agent-scope loads: sc1, no stale L2)
    unsigned hr = 0u;
    if (s > 0){
      unsigned long long v = v0;
      while ((unsigned)(v>>32) != (unsigned)s){
        v = __hip_atomic_load(&exd[((s&1)<<7) + rb + l],
                              __ATOMIC_RELAXED, __HIP_MEMORY_SCOPE_AGENT);
      }
      hr = (unsigned)v;
    }
    // --- prefetch next xg AFTER the poll (poll waits must not drain HBM loads)
    float nxg0 = 0.f, nxg1 = 0.f;
    if (s+1 < LSEQ){
      int tn = d ? (LSEQ-2-s) : (s+1);
      nxg0 = xgd[(size_t)tn*1024 + r0];
      nxg1 = xgd[(size_t)tn*1024 + r1];
    }
    // --- remote-half dot (hr lane k = global pair rb+k; w[64+k] = pair rb+k)
    #pragma unroll
    for (int k=0;k<64;k+=2){
      unsigned pa = __builtin_amdgcn_readlane(hr,k);
      unsigned pb = __builtin_amdgcn_readlane(hr,k+1);
      half2v va = __builtin_bit_cast(half2v,pa);
      half2v vb = __builtin_bit_cast(half2v,pb);
      a0 = __builtin_amdgcn_fdot2(va, w0[64+k],   a0, false);
      a1 = __builtin_amdgcn_fdot2(va, w1[64+k],   a1, false);
      b0 = __builtin_amdgcn_fdot2(vb, w0[64+k+1], b0, false);
      b1 = __builtin_amdgcn_fdot2(vb, w1[64+k+1], b1, false);
    }
    float pre0 = a0 + b0;
    float pre1 = a1 + b1;
    float act0, act1;
    if (g == 2){ act0 = tanh_fast(pre0); act1 = tanh_fast(pre1); }
    else       { act0 = sigm(pre0);      act1 = sigm(pre1); }
    gate_sh[g*128 + l]      = act0;
    gate_sh[g*128 + 64 + l] = act1;
    xg0 = nxg0; xg1 = nxg1;
    __syncthreads();
    if (tid < 64){
      int m = tid;
      float2 gi = *(const float2*)&gate_sh[      2*m];
      float2 gf = *(const float2*)&gate_sh[128 + 2*m];
      float2 gg = *(const float2*)&gate_sh[256 + 2*m];
      float2 go = *(const float2*)&gate_sh[384 + 2*m];
      c0 = gf.x*c0 + gi.x*gg.x;
      c1 = gf.y*c1 + gi.y*gg.y;
      float h0 = go.x * tanh_fast(c0);
      float h1 = go.y * tanh_fast(c1);
      hp = __builtin_bit_cast(unsigned, pack2(h0,h1));
      h2loc[m] = hp;
    }
    __syncthreads();
  }
  // final h history store (step LSEQ-1)
  if (tid < 64){
    int tl = d ? 0 : (LSEQ-1);
    *(unsigned*)&hd[(size_t)tl*256 + 128*c + 2*tid] = hp;
  }
}

// K3: feats[t][tag] = b_out[tag] + [hf|hb] . w_out[tag]   (h history is f16)
__global__ void feats_kernel(
    const unsigned short* hstH, const float* w_out, const float* b_out,
    float* feats)
{
  __shared__ float w_sh[12*520];
  __shared__ float h_sh[16*520];
  const _Float16* hf = (const _Float16*)hstH;
  int tid=threadIdx.x;
  int t0=blockIdx.x*16;
  for (int i=tid;i<12*512;i+=256){ int tag=i>>9,k=i&511; w_sh[tag*520+k]=w_out[i]; }
  for (int i=tid;i<16*512;i+=256){
    int tt=i>>9,k=i&511;
    float v = (k<256)? (float)hf[(size_t)(t0+tt)*256+k]
                     : (float)hf[(size_t)(LSEQ+t0+tt)*256 + (k-256)];
    h_sh[tt*520+k]=v;
  }
  __syncthreads();
  if (tid<192){
    int tt=tid/12, tag=tid%12;
    const float* wr=&w_sh[tag*520];
    const float* hr=&h_sh[tt*520];
    float acc=b_out[tag];
    for (int k=0;k<512;k+=4){
      float4 a=*(const float4*)(wr+k);
      float4 b=*(const float4*)(hr+k);
      acc += a.x*b.x+a.y*b.y+a.z*b.z+a.w*b.w;
    }
    feats[(size_t)(t0+tt)*12+tag]=acc;
  }
}

// K4: Viterbi DP: feats in LDS, v register-resident via readlane; parallel
// block-composed backtrack.
__global__ void BiLSTM_CRF_14405320311361_kernel(
    const float* feats, const float* trans, float* outp)
{
  __shared__ float fsh[LSEQ*12];           // 96 KB
  __shared__ unsigned char bps[LSEQ*12];   // 24 KB
  __shared__ float term_sh[16];
  __shared__ int ibuf[66];
  __shared__ unsigned char fmap[64*12];
  int tid = threadIdx.x;
  for (int i=tid; i<LSEQ*12/4; i+=256)
    *(float4*)&fsh[4*i] = *(const float4*)&feats[4*i];
  __syncthreads();

  int lane = tid & 63;
  int fl = (lane<12) ? lane : 0;
  float vn = 0.f;
  if (tid < 64){
    float tr[12];
    #pragma unroll
    for (int p=0;p<12;++p) tr[p] = trans[fl*12+p];
    vn = (lane==10) ? 0.f : -10000.f;     // START=10
    float fa = fsh[fl];
    float fb = fsh[12+fl];
    for (int t=0;t<LSEQ;++t){
      unsigned vu = __float_as_uint(vn);
      float best; int bp; float sc;
      best = tr[0] + __uint_as_float(__builtin_amdgcn_readlane(vu,0)); bp = 0;
      sc = tr[1]  + __uint_as_float(__builtin_amdgcn_readlane(vu,1));  if(sc>best){best=sc;bp=1;}
      sc = tr[2]  + __uint_as_float(__builtin_amdgcn_readlane(vu,2));  if(sc>best){best=sc;bp=2;}
      sc = tr[3]  + __uint_as_float(__builtin_amdgcn_readlane(vu,3));  if(sc>best){best=sc;bp=3;}
      sc = tr[4]  + __uint_as_float(__builtin_amdgcn_readlane(vu,4));  if(sc>best){best=sc;bp=4;}
      sc = tr[5]  + __uint_as_float(__builtin_amdgcn_readlane(vu,5));  if(sc>best){best=sc;bp=5;}
      sc = tr[6]  + __uint_as_float(__builtin_amdgcn_readlane(vu,6));  if(sc>best){best=sc;bp=6;}
      sc = tr[7]  + __uint_as_float(__builtin_amdgcn_readlane(vu,7));  if(sc>best){best=sc;bp=7;}
      sc = tr[8]  + __uint_as_float(__builtin_amdgcn_readlane(vu,8));  if(sc>best){best=sc;bp=8;}
      sc = tr[9]  + __uint_as_float(__builtin_amdgcn_readlane(vu,9));  if(sc>best){best=sc;bp=9;}
      sc = tr[10] + __uint_as_float(__builtin_amdgcn_readlane(vu,10)); if(sc>best){best=sc;bp=10;}
      sc = tr[11] + __uint_as_float(__builtin_amdgcn_readlane(vu,11)); if(sc>best){best=sc;bp=11;}
      vn = best + fa;
      fa = fb;
      if (t+2 < LSEQ) fb = fsh[(t+2)*12+fl];
      if (lane<12) bps[t*12+lane] = (unsigned char)bp;
    }
  }
  if (tid < 12) term_sh[tid] = vn + trans[11*12+tid];   // STOP=11
  __syncthreads();
  if (tid == 0){
    float bs=term_sh[0]; int bt=0;
    for (int p=1;p<12;++p){ if (term_sh[p]>bs){bs=term_sh[p];bt=p;} }
    outp[0] = bs;
    ibuf[64] = bt;
  }
  __syncthreads();
  if (tid < 64){
    int b = tid;
    int f[12];
    int thi = b*32+31;
    #pragma unroll
    for (int x=0;x<12;++x) f[x] = bps[thi*12+x];
    for (int t=thi-1; t>=b*32; --t){
      int base = t*12;
      #pragma unroll
      for (int x=0;x<12;++x) f[x] = bps[base + f[x]];
    }
    #pragma unroll
    for (int x=0;x<12;++x) fmap[b*12+x] = (unsigned char)f[x];
  }
  __syncthreads();
  if (tid == 0){
    int tag = ibuf[64];
    for (int b=63;b>=0;--b){ ibuf[b]=tag; tag = fmap[b*12+tag]; }
  }
  __syncthreads();
  if (tid < 64){
    int b = tid;
    int tag = ibuf[b];
    for (int t=b*32+31; t>=b*32; --t){
      outp[1+t] = (float)tag;
      tag = bps[t*12+tag];
    }
  }
}

extern "C" void kernel_launch(void* const* d_in, const int* in_sizes, int n_in,
                              void* d_out, int out_size, void* d_ws, size_t ws_size,
                              hipStream_t stream) {
  const int*   sent   = (const int*)d_in[0];
  const float* embed  = (const float*)d_in[1];
  const float* w_ih_f = (const float*)d_in[2];
  const float* w_hh_f = (const float*)d_in[3];
  const float* b_ih_f = (const float*)d_in[4];
  const float* b_hh_f = (const float*)d_in[5];
  const float* w_ih_b = (const float*)d_in[6];
  const float* w_hh_b = (const float*)d_in[7];
  const float* b_ih_b = (const float*)d_in[8];
  const float* b_hh_b = (const float*)d_in[9];
  const float* w_out  = (const float*)d_in[10];
  const float* b_out  = (const float*)d_in[11];
  const float* trans  = (const float*)d_in[12];

  float* xg = (float*)d_ws;                                           // [2][L][1024] f32 = 16 MB
  unsigned short* hstH = (unsigned short*)(xg + (size_t)2*LSEQ*1024); // [2][L][256] f16 = 2 MB
  unsigned long long* ex = (unsigned long long*)(hstH + (size_t)2*LSEQ*256); // 8 KB
  float* feats = (float*)(ex + 1024);                                 // [L][12] f32 = 96 KB
  float* outp  = (float*)d_out;

  init_kernel<<<dim3(4), dim3(256), 0, stream>>>(ex);
  xg_kernel<<<dim3(LSEQ/8), dim3(256), 0, stream>>>(
      sent, embed, w_ih_f, b_ih_f, b_hh_f, w_ih_b, b_ih_b, b_hh_b, xg);
  lstm_rec<<<dim3(16), dim3(256), 0, stream>>>(w_hh_f, w_hh_b, xg, hstH, ex);
  feats_kernel<<<dim3(LSEQ/16), dim3(256), 0, stream>>>(hstH, w_out, b_out, feats);
  BiLSTM_CRF_14405320311361_kernel<<<dim3(1), dim3(256), 0, stream>>>(feats, trans, outp);
}

// Round 10
// 3540.418 us; speedup vs baseline: 4.5108x; 1.4278x over previous
//
#include <hip/hip_runtime.h>

#define LSEQ 2048
#define TAGS 12

typedef _Float16 half2v __attribute__((ext_vector_type(2)));
typedef unsigned long long u64;

__device__ __forceinline__ float sigm(float x){ return 1.0f/(1.0f+__expf(-x)); }
__device__ __forceinline__ float tanh_fast(float x){ return 1.0f - 2.0f/(1.0f+__expf(2.0f*x)); }
__device__ __forceinline__ half2v pack2(float a, float b){
  half2v r; r.x=(_Float16)a; r.y=(_Float16)b; return r;
}

// K0: zero the exchange buffer (tag 0 never matches step tags in [1,2047]).
__global__ void init_kernel(u64* ex)
{
  int tid = blockIdx.x*256 + threadIdx.x;
  if (tid < 1024) ex[tid] = 0ull;
}

// K1: xg[d][t][row] = b_ih[row]+b_hh[row] + sum_e embed[sent[t]][e] * w_ih[row][e]
__global__ void xg_kernel(
    const int* sent, const float* embed,
    const float* w_ih_f, const float* b_ih_f, const float* b_hh_f,
    const float* w_ih_b, const float* b_ih_b, const float* b_hh_b,
    float* xg)
{
  __shared__ float x_sh[8][256];
  int tid = threadIdx.x;
  int t0 = blockIdx.x * 8;
  for (int i=0;i<8;++i){
    int idx = sent[t0+i];
    x_sh[i][tid] = embed[(size_t)idx*256 + tid];
  }
  __syncthreads();
  for (int ri=0; ri<8; ++ri){
    int r = ri*256 + tid;
    int d = r >> 10;
    int row = r & 1023;
    const float* wr = (d ? w_ih_b : w_ih_f) + (size_t)row*256;
    const float* bi = d ? b_ih_b : b_ih_f;
    const float* bh = d ? b_hh_b : b_hh_f;
    float acc[8];
    #pragma unroll
    for (int i=0;i<8;++i) acc[i]=0.f;
    for (int k0=0;k0<256;k0+=4){
      float4 p = *(const float4*)(wr + k0);
      #pragma unroll
      for (int i=0;i<8;++i){
        acc[i] += p.x*x_sh[i][k0] + p.y*x_sh[i][k0+1]
                + p.z*x_sh[i][k0+2] + p.w*x_sh[i][k0+3];
      }
    }
    float bias = bi[row] + bh[row];
    #pragma unroll
    for (int i=0;i<8;++i)
      xg[((size_t)d*LSEQ + (size_t)(t0+i))*1024 + row] = acc[i] + bias;
  }
}

// K2: bidirectional LSTM recurrence, 4 CUs/direction, SPILL-FREE by design:
// 1 gate-row per thread -> 128 half2v weight regs + ~40 working (< 256).
// Rounds 5-9 all sat at >=296 regs -> scratch/AGPR shuttling every step
// (invariant ~11.5 GB FETCH regardless of poll mechanism).
// Blocks {0,8,16,24}=dir0, {1,9,17,25}=dir1 (same-XCD bet, %8 round-robin).
// Weight columns permuted [own | q+1 | q+2 | q+3] -> register indices all
// compile-time. Exchange: CU q sends its 32 h-pairs tag-packed (atomicExch);
// threads 64..159 poll peers with agent-scope loads issued BEFORE the local
// dot. All-to-all polling makes parity-slot reuse safe (sender at s+2 implies
// it consumed every peer's s+1, implying those peers finished step s reads).
__global__ __launch_bounds__(256,1) void lstm_rec(
    const float* __restrict__ w_hh_f, const float* __restrict__ w_hh_b,
    const float* __restrict__ xg, unsigned short* __restrict__ hstH,
    u64* __restrict__ ex)
{
  int blk = blockIdx.x;
  int d = blk & 7;
  if (d > 1) return;
  int q = blk >> 3;                 // quad: owns units [64q, 64q+64)
  int qa = (q+1)&3, qb = (q+2)&3, qc = (q+3)&3;

  int tid = threadIdx.x;
  int g = tid >> 6, l = tid & 63;
  int row = g*256 + 64*q + l;       // gate rows (PyTorch order i,f,g,o)
  const float* W = d ? w_hh_b : w_hh_f;
  const float* xgd = xg + (size_t)d*LSEQ*1024;
  unsigned short* hd = hstH + (size_t)d*LSEQ*256;
  u64* exd = ex + (size_t)d*256;    // [2 parity][128 pairs]

  __shared__ float gate_sh[256];    // [gate][64 units]
  __shared__ unsigned h2all[128];   // all 128 packed f16 h-pairs

  // Permuted-column weights: w[0..31]=own pairs, then peers qa, qb, qc.
  half2v w[128];
  {
    const float* p0 = W + (size_t)row*256 + 64*q;
    const float* p1 = W + (size_t)row*256 + 64*qa;
    const float* p2 = W + (size_t)row*256 + 64*qb;
    const float* p3 = W + (size_t)row*256 + 64*qc;
    #pragma unroll
    for (int k0=0;k0<16;++k0){
      float4 a = *(const float4*)(p0+4*k0);
      w[2*k0]      = pack2(a.x,a.y);  w[2*k0+1]    = pack2(a.z,a.w);
      float4 b = *(const float4*)(p1+4*k0);
      w[32+2*k0]   = pack2(b.x,b.y);  w[32+2*k0+1] = pack2(b.z,b.w);
      float4 cc= *(const float4*)(p2+4*k0);
      w[64+2*k0]   = pack2(cc.x,cc.y); w[64+2*k0+1] = pack2(cc.z,cc.w);
      float4 e = *(const float4*)(p3+4*k0);
      w[96+2*k0]   = pack2(e.x,e.y);  w[96+2*k0+1] = pack2(e.z,e.w);
    }
  }
  if (tid < 128) h2all[tid] = 0u;
  float c0 = 0.f, c1 = 0.f;         // cell state (tid<32)
  unsigned hp = 0u;                 // our h-pair from prev step (tid<32)

  // loop-invariant addresses
  int pollj = tid - 64;                         // 0..95 for pollers
  int pollpeer = (q + 1 + (pollj>>5)) & 3;
  int pollslot = 32*pollpeer + (pollj & 31);    // valid when 64<=tid<160
  int adrA = (l < 32) ? (32*qa + l) : (32*qb + (l-32));
  int adrB = 32*qc + (l & 31);
  int adrL = 32*q + (l & 31);
  __syncthreads();

  int tf = d ? (LSEQ-1) : 0;
  float xg0 = xgd[(size_t)tf*1024 + row];

  for (int s=0;s<LSEQ;++s){
    // --- top: publish prev-h to peers + h history (fire-and-forget)
    if (s > 0 && tid < 32){
      atomicExch(&exd[((s&1)<<7) + 32*q + tid], ((u64)(unsigned)s << 32) | (u64)hp);
      int tp = d ? (LSEQ-s) : (s-1);
      *(unsigned*)&hd[(size_t)tp*256 + 64*q + 2*tid] = hp;
    }
    // --- pollers: issue first probe early (hides under local dot)
    u64 v0 = 0ull;
    bool poller = (s > 0) && (tid >= 64) && (tid < 160);
    if (poller)
      v0 = __hip_atomic_load(&exd[((s&1)<<7) + pollslot],
                             __ATOMIC_RELAXED, __HIP_MEMORY_SCOPE_AGENT);
    // --- local quarter dot (own 32 pairs, in LDS since prev step)
    unsigned hl = h2all[adrL];
    float a0=xg0, a1=0.f, a2=0.f, a3=0.f;
    #pragma unroll
    for (int k=0;k<32;k+=4){
      unsigned p0v = __builtin_amdgcn_readlane(hl,k);
      unsigned p1v = __builtin_amdgcn_readlane(hl,k+1);
      unsigned p2v = __builtin_amdgcn_readlane(hl,k+2);
      unsigned p3v = __builtin_amdgcn_readlane(hl,k+3);
      a0 = __builtin_amdgcn_fdot2(__builtin_bit_cast(half2v,p0v), w[k],   a0, false);
      a1 = __builtin_amdgcn_fdot2(__builtin_bit_cast(half2v,p1v), w[k+1], a1, false);
      a2 = __builtin_amdgcn_fdot2(__builtin_bit_cast(half2v,p2v), w[k+2], a2, false);
      a3 = __builtin_amdgcn_fdot2(__builtin_bit_cast(half2v,p3v), w[k+3], a3, false);
    }
    // --- finish poll, write remote pairs to LDS
    if (poller){
      u64 v = v0;
      while ((unsigned)(v>>32) != (unsigned)s)
        v = __hip_atomic_load(&exd[((s&1)<<7) + pollslot],
                              __ATOMIC_RELAXED, __HIP_MEMORY_SCOPE_AGENT);
      h2all[pollslot] = (unsigned)v;
    }
    // --- prefetch next xg (after poll: its latency hides under remote dot)
    float nxg = 0.f;
    if (s+1 < LSEQ){
      int tn = d ? (LSEQ-2-s) : (s+1);
      nxg = xgd[(size_t)tn*1024 + row];
    }
    __syncthreads();
    // --- remote 3/4 dot: hrA lanes 0-31 = peer qa pairs, 32-63 = peer qb;
    //     hrB lanes 0-31 = peer qc pairs. All readlane/reg indices static.
    unsigned hrA = h2all[adrA];
    unsigned hrB = h2all[adrB];
    #pragma unroll
    for (int k=0;k<32;k+=2){
      unsigned pA0 = __builtin_amdgcn_readlane(hrA, k);
      unsigned pA1 = __builtin_amdgcn_readlane(hrA, k+1);
      unsigned pB0 = __builtin_amdgcn_readlane(hrA, 32+k);
      unsigned pB1 = __builtin_amdgcn_readlane(hrA, 32+k+1);
      unsigned pC0 = __builtin_amdgcn_readlane(hrB, k);
      unsigned pC1 = __builtin_amdgcn_readlane(hrB, k+1);
      a0 = __builtin_amdgcn_fdot2(__builtin_bit_cast(half2v,pA0), w[32+k],   a0, false);
      a1 = __builtin_amdgcn_fdot2(__builtin_bit_cast(half2v,pA1), w[32+k+1], a1, false);
      a2 = __builtin_amdgcn_fdot2(__builtin_bit_cast(half2v,pB0), w[64+k],   a2, false);
      a3 = __builtin_amdgcn_fdot2(__builtin_bit_cast(half2v,pB1), w[64+k+1], a3, false);
      a0 = __builtin_amdgcn_fdot2(__builtin_bit_cast(half2v,pC0), w[96+k],   a0, false);
      a1 = __builtin_amdgcn_fdot2(__builtin_bit_cast(half2v,pC1), w[96+k+1], a1, false);
    }
    float pre = (a0+a1) + (a2+a3);
    float act = (g==2) ? tanh_fast(pre) : sigm(pre);
    gate_sh[tid] = act;               // [g][64]: tid = g*64 + l
    xg0 = nxg;
    __syncthreads();
    // --- update: tid<32 handles units 64q+2m, 64q+2m+1
    if (tid < 32){
      int m = tid;
      float2 gi = *(const float2*)&gate_sh[      2*m];
      float2 gf = *(const float2*)&gate_sh[ 64 + 2*m];
      float2 gg = *(const float2*)&gate_sh[128 + 2*m];
      float2 go = *(const float2*)&gate_sh[192 + 2*m];
      c0 = gf.x*c0 + gi.x*gg.x;
      c1 = gf.y*c1 + gi.y*gg.y;
      float h0 = go.x * tanh_fast(c0);
      float h1 = go.y * tanh_fast(c1);
      hp = __builtin_bit_cast(unsigned, pack2(h0,h1));
      h2all[32*q + m] = hp;
    }
    __syncthreads();
  }
  // final h history store (data of step LSEQ-1)
  if (tid < 32){
    int tl = d ? 0 : (LSEQ-1);
    *(unsigned*)&hd[(size_t)tl*256 + 64*q + 2*tid] = hp;
  }
}

// K3: feats[t][tag] = b_out[tag] + [hf|hb] . w_out[tag]   (h history is f16)
__global__ void feats_kernel(
    const unsigned short* hstH, const float* w_out, const float* b_out,
    float* feats)
{
  __shared__ float w_sh[12*520];
  __shared__ float h_sh[16*520];
  const _Float16* hf = (const _Float16*)hstH;
  int tid=threadIdx.x;
  int t0=blockIdx.x*16;
  for (int i=tid;i<12*512;i+=256){ int tag=i>>9,k=i&511; w_sh[tag*520+k]=w_out[i]; }
  for (int i=tid;i<16*512;i+=256){
    int tt=i>>9,k=i&511;
    float v = (k<256)? (float)hf[(size_t)(t0+tt)*256+k]
                     : (float)hf[(size_t)(LSEQ+t0+tt)*256 + (k-256)];
    h_sh[tt*520+k]=v;
  }
  __syncthreads();
  if (tid<192){
    int tt=tid/12, tag=tid%12;
    const float* wr=&w_sh[tag*520];
    const float* hr=&h_sh[tt*520];
    float acc=b_out[tag];
    for (int k=0;k<512;k+=4){
      float4 a=*(const float4*)(wr+k);
      float4 b=*(const float4*)(hr+k);
      acc += a.x*b.x+a.y*b.y+a.z*b.z+a.w*b.w;
    }
    feats[(size_t)(t0+tt)*12+tag]=acc;
  }
}

// K4: Viterbi DP: feats in LDS, v register-resident via readlane; parallel
// block-composed backtrack.
__global__ void BiLSTM_CRF_14405320311361_kernel(
    const float* feats, const float* trans, float* outp)
{
  __shared__ float fsh[LSEQ*12];           // 96 KB
  __shared__ unsigned char bps[LSEQ*12];   // 24 KB
  __shared__ float term_sh[16];
  __shared__ int ibuf[66];
  __shared__ unsigned char fmap[64*12];
  int tid = threadIdx.x;
  for (int i=tid; i<LSEQ*12/4; i+=256)
    *(float4*)&fsh[4*i] = *(const float4*)&feats[4*i];
  __syncthreads();

  int lane = tid & 63;
  int fl = (lane<12) ? lane : 0;
  float vn = 0.f;
  if (tid < 64){
    float tr[12];
    #pragma unroll
    for (int p=0;p<12;++p) tr[p] = trans[fl*12+p];
    vn = (lane==10) ? 0.f : -10000.f;     // START=10
    float fa = fsh[fl];
    float fb = fsh[12+fl];
    for (int t=0;t<LSEQ;++t){
      unsigned vu = __float_as_uint(vn);
      float best; int bp; float sc;
      best = tr[0] + __uint_as_float(__builtin_amdgcn_readlane(vu,0)); bp = 0;
      sc = tr[1]  + __uint_as_float(__builtin_amdgcn_readlane(vu,1));  if(sc>best){best=sc;bp=1;}
      sc = tr[2]  + __uint_as_float(__builtin_amdgcn_readlane(vu,2));  if(sc>best){best=sc;bp=2;}
      sc = tr[3]  + __uint_as_float(__builtin_amdgcn_readlane(vu,3));  if(sc>best){best=sc;bp=3;}
      sc = tr[4]  + __uint_as_float(__builtin_amdgcn_readlane(vu,4));  if(sc>best){best=sc;bp=4;}
      sc = tr[5]  + __uint_as_float(__builtin_amdgcn_readlane(vu,5));  if(sc>best){best=sc;bp=5;}
      sc = tr[6]  + __uint_as_float(__builtin_amdgcn_readlane(vu,6));  if(sc>best){best=sc;bp=6;}
      sc = tr[7]  + __uint_as_float(__builtin_amdgcn_readlane(vu,7));  if(sc>best){best=sc;bp=7;}
      sc = tr[8]  + __uint_as_float(__builtin_amdgcn_readlane(vu,8));  if(sc>best){best=sc;bp=8;}
      sc = tr[9]  + __uint_as_float(__builtin_amdgcn_readlane(vu,9));  if(sc>best){best=sc;bp=9;}
      sc = tr[10] + __uint_as_float(__builtin_amdgcn_readlane(vu,10)); if(sc>best){best=sc;bp=10;}
      sc = tr[11] + __uint_as_float(__builtin_amdgcn_readlane(vu,11)); if(sc>best){best=sc;bp=11;}
      vn = best + fa;
      fa = fb;
      if (t+2 < LSEQ) fb = fsh[(t+2)*12+fl];
      if (lane<12) bps[t*12+lane] = (unsigned char)bp;
    }
  }
  if (tid < 12) term_sh[tid] = vn + trans[11*12+tid];   // STOP=11
  __syncthreads();
  if (tid == 0){
    float bs=term_sh[0]; int bt=0;
    for (int p=1;p<12;++p){ if (term_sh[p]>bs){bs=term_sh[p];bt=p;} }
    outp[0] = bs;
    ibuf[64] = bt;
  }
  __syncthreads();
  if (tid < 64){
    int b = tid;
    int f[12];
    int thi = b*32+31;
    #pragma unroll
    for (int x=0;x<12;++x) f[x] = bps[thi*12+x];
    for (int t=thi-1; t>=b*32; --t){
      int base = t*12;
      #pragma unroll
      for (int x=0;x<12;++x) f[x] = bps[base + f[x]];
    }
    #pragma unroll
    for (int x=0;x<12;++x) fmap[b*12+x] = (unsigned char)f[x];
  }
  __syncthreads();
  if (tid == 0){
    int tag = ibuf[64];
    for (int b=63;b>=0;--b){ ibuf[b]=tag; tag = fmap[b*12+tag]; }
  }
  __syncthreads();
  if (tid < 64){
    int b = tid;
    int tag = ibuf[b];
    for (int t=b*32+31; t>=b*32; --t){
      outp[1+t] = (float)tag;
      tag = bps[t*12+tag];
    }
  }
}

extern "C" void kernel_launch(void* const* d_in, const int* in_sizes, int n_in,
                              void* d_out, int out_size, void* d_ws, size_t ws_size,
                              hipStream_t stream) {
  const int*   sent   = (const int*)d_in[0];
  const float* embed  = (const float*)d_in[1];
  const float* w_ih_f = (const float*)d_in[2];
  const float* w_hh_f = (const float*)d_in[3];
  const float* b_ih_f = (const float*)d_in[4];
  const float* b_hh_f = (const float*)d_in[5];
  const float* w_ih_b = (const float*)d_in[6];
  const float* w_hh_b = (const float*)d_in[7];
  const float* b_ih_b = (const float*)d_in[8];
  const float* b_hh_b = (const float*)d_in[9];
  const float* w_out  = (const float*)d_in[10];
  const float* b_out  = (const float*)d_in[11];
  const float* trans  = (const float*)d_in[12];

  float* xg = (float*)d_ws;                                           // [2][L][1024] f32 = 16 MB
  unsigned short* hstH = (unsigned short*)(xg + (size_t)2*LSEQ*1024); // [2][L][256] f16 = 2 MB
  u64* ex = (u64*)(hstH + (size_t)2*LSEQ*256);                        // 8 KB
  float* feats = (float*)(ex + 1024);                                 // [L][12] f32 = 96 KB
  float* outp  = (float*)d_out;

  init_kernel<<<dim3(4), dim3(256), 0, stream>>>(ex);
  xg_kernel<<<dim3(LSEQ/8), dim3(256), 0, stream>>>(
      sent, embed, w_ih_f, b_ih_f, b_hh_f, w_ih_b, b_ih_b, b_hh_b, xg);
  lstm_rec<<<dim3(32), dim3(256), 0, stream>>>(w_hh_f, w_hh_b, xg, hstH, ex);
  feats_kernel<<<dim3(LSEQ/16), dim3(256), 0, stream>>>(hstH, w_out, b_out, feats);
  BiLSTM_CRF_14405320311361_kernel<<<dim3(1), dim3(256), 0, stream>>>(feats, trans, outp);
}